// Round 1
// baseline (3201.995 us; speedup 1.0000x reference)
//
#include <hip/hip_runtime.h>
#include <hip/hip_bf16.h>

// Problem constants
#define T_TOK 8192   // B*S
#define HDIM  2048
#define FDIM  8192
#define NEXP  8

typedef __attribute__((ext_vector_type(8))) __bf16 bf16x8;
typedef __attribute__((ext_vector_type(4))) float  f32x4;

__device__ __forceinline__ void gload_lds16(const void* g, void* l) {
    __builtin_amdgcn_global_load_lds((const __attribute__((address_space(1))) void*)g,
                                     (__attribute__((address_space(3))) void*)l, 16, 0, 0);
}

// ---------------- zero counts ----------------
__global__ void zero_counts_kernel(int* c) {
    if (threadIdx.x < NEXP) c[threadIdx.x] = 0;
}

// ---------------- gate: logits, top-2, routing lists, bf16 copy of tokens ----------------
__global__ void gate_kernel(const float* __restrict__ hidden, const float* __restrict__ gate_w,
                            __hip_bfloat16* __restrict__ X, unsigned* __restrict__ list_tok,
                            float* __restrict__ list_w, int* __restrict__ counts) {
    const int wave = threadIdx.x >> 6, lane = threadIdx.x & 63;
    const int t = blockIdx.x * 4 + wave;            // 2048 blocks * 4 waves = 8192 tokens
    const float* hrow = hidden + (size_t)t * HDIM;
    __hip_bfloat16* xrow = X + (size_t)t * HDIM;

    float acc[NEXP] = {0.f,0.f,0.f,0.f,0.f,0.f,0.f,0.f};
#pragma unroll 4
    for (int i = 0; i < HDIM / 64; ++i) {
        const int idx = i * 64 + lane;
        const float h = hrow[idx];
        xrow[idx] = __float2bfloat16(h);
        const float4* gw = (const float4*)(gate_w + (size_t)idx * NEXP);
        float4 g0 = gw[0], g1 = gw[1];
        acc[0] += h * g0.x; acc[1] += h * g0.y; acc[2] += h * g0.z; acc[3] += h * g0.w;
        acc[4] += h * g1.x; acc[5] += h * g1.y; acc[6] += h * g1.z; acc[7] += h * g1.w;
    }
    // full-wave butterfly reduce each of the 8 logits
#pragma unroll
    for (int off = 32; off >= 1; off >>= 1)
#pragma unroll
        for (int e = 0; e < NEXP; ++e) acc[e] += __shfl_xor(acc[e], off, 64);

    if (lane == 0) {
        int e0 = 0; float l0 = acc[0];
#pragma unroll
        for (int e = 1; e < NEXP; ++e) if (acc[e] > l0) { l0 = acc[e]; e0 = e; }
        int e1 = -1; float l1 = -3.4e38f;
#pragma unroll
        for (int e = 0; e < NEXP; ++e) if (e != e0 && acc[e] > l1) { l1 = acc[e]; e1 = e; }
        // softmax denominator cancels: w0 = p0/(p0+p1) = 1/(1+exp(l1-l0))
        const float r = __expf(l1 - l0) == 0.f ? expf(l1 - l0) : expf(l1 - l0);
        const float w0 = 1.f / (1.f + r);
        const float w1 = 1.f - w0;
        int p0 = atomicAdd(&counts[e0], 1);
        list_tok[e0 * T_TOK + p0] = (unsigned)(t * 2 + 0);
        list_w [e0 * T_TOK + p0] = w0;
        int p1 = atomicAdd(&counts[e1], 1);
        list_tok[e1 * T_TOK + p1] = (unsigned)(t * 2 + 1);
        list_w [e1 * T_TOK + p1] = w1;
    }
}

// ---------------- transpose + cast fp32 [K][N] -> bf16 [N][K] ----------------
__global__ void transpose_bf16_kernel(const float* __restrict__ W, __hip_bfloat16* __restrict__ Wt,
                                      int K, int N) {
    __shared__ float tile[64][65];
    const int tid = threadIdx.x;
    const int k0 = blockIdx.y * 64, n0 = blockIdx.x * 64;
    const int rr = tid >> 6, cc = tid & 63;
#pragma unroll
    for (int i = 0; i < 16; ++i) {
        const int r = i * 4 + rr;
        tile[r][cc] = W[(size_t)(k0 + r) * N + n0 + cc];
    }
    __syncthreads();
#pragma unroll
    for (int i = 0; i < 16; ++i) {
        const int r = i * 4 + rr;                      // output row = N index
        Wt[(size_t)(n0 + r) * K + k0 + cc] = __float2bfloat16(tile[cc][r]);
    }
}

// ---------------- grouped GEMM tile: 128x128, BK=64, 4 waves, 16x16x32 bf16 MFMA ----------------
// MODE 0: Y1[pos] = gelu(gather(X)[pos] @ W1t^T + b1)   (A rows gathered via token list)
// MODE 1: r[code] = (Y1[pos] @ W2t^T + b2) * w[pos]     (scatter by code = 2*t+slot)
template <int MODE>
__global__ void moe_gemm_kernel(const __hip_bfloat16* __restrict__ A,
                                const __hip_bfloat16* __restrict__ Bt,   // [N][K] bf16
                                const float* __restrict__ bias,          // [N]
                                const unsigned* __restrict__ list_tok,
                                const float* __restrict__ list_w,
                                const int* __restrict__ count,
                                int K, int N,
                                __hip_bfloat16* __restrict__ Y1,
                                float* __restrict__ r) {
    const int n_e = *count;
    const int m0 = blockIdx.y * 128;
    if (m0 >= n_e) return;                       // early-exit inactive row tiles
    const int n0 = blockIdx.x * 128;

    __shared__ __align__(16) char smem[32768];   // A tile 16KB @0, B tile 16KB @16384

    const int tid = threadIdx.x, wave = tid >> 6, lane = tid & 63;
    const int wm = wave >> 1, wn = wave & 1;

    // staging descriptors: 4 chunks each for A and B; chunk idx -> (row, kbyte)
    const char* aBase[4];
    const char* bBase[4];
    int ldsOff[4];
#pragma unroll
    for (int c = 0; c < 4; ++c) {
        const int idx = (c * 4 + wave) * 64 + lane;   // 0..1023
        const int row = idx >> 3;
        const int kb  = (idx & 7) << 4;
        const int kbs = kb ^ ((row & 7) << 4);        // inverse-swizzled source (rule 21)
        int pos = m0 + row; if (pos > n_e - 1) pos = n_e - 1;
        const int arow = (MODE == 0) ? (int)(list_tok[pos] >> 1) : pos;
        aBase[c] = (const char*)A  + ((size_t)arow * K) * 2 + kbs;
        bBase[c] = (const char*)Bt + ((size_t)(n0 + row) * K) * 2 + kbs;
        ldsOff[c] = idx * 16;
    }

    f32x4 acc[4][4] = {};
    const int l15 = lane & 15;
    const int lkb = (lane >> 4) << 4;     // byte offset of this lane's K-group (8 bf16 = 16B)

    const int ksteps = K >> 6;
    for (int ks = 0; ks < ksteps; ++ks) {
        const size_t koff = (size_t)ks * 128;  // 64 bf16 = 128 bytes per K-step
#pragma unroll
        for (int c = 0; c < 4; ++c) {
            gload_lds16(aBase[c] + koff, smem + ldsOff[c]);
            gload_lds16(bBase[c] + koff, smem + 16384 + ldsOff[c]);
        }
        asm volatile("s_waitcnt vmcnt(0)" ::: "memory");
        __syncthreads();
#pragma unroll
        for (int kk = 0; kk < 2; ++kk) {
            bf16x8 af[4], bfr[4];
#pragma unroll
            for (int m = 0; m < 4; ++m) {
                const int row = wm * 64 + m * 16 + l15;
                const int off = row * 128 + ((kk * 64 + lkb) ^ ((row & 7) << 4));
                af[m] = *(const bf16x8*)(smem + off);
            }
#pragma unroll
            for (int n = 0; n < 4; ++n) {
                const int row = wn * 64 + n * 16 + l15;
                const int off = row * 128 + ((kk * 64 + lkb) ^ ((row & 7) << 4));
                bfr[n] = *(const bf16x8*)(smem + 16384 + off);
            }
#pragma unroll
            for (int m = 0; m < 4; ++m)
#pragma unroll
                for (int n = 0; n < 4; ++n)
                    acc[m][n] = __builtin_amdgcn_mfma_f32_16x16x32_bf16(af[m], bfr[n], acc[m][n], 0, 0, 0);
        }
        __syncthreads();
    }

    // epilogue: C/D layout col = lane&15, row = (lane>>4)*4 + j  [m89-verified]
#pragma unroll
    for (int m = 0; m < 4; ++m) {
        const int rbase = wm * 64 + m * 16 + ((lane >> 4) << 2);
#pragma unroll
        for (int n = 0; n < 4; ++n) {
            const int col = n0 + wn * 64 + n * 16 + l15;
            const float b = bias[col];
#pragma unroll
            for (int j = 0; j < 4; ++j) {
                const int pos = m0 + rbase + j;
                if (pos < n_e) {
                    const float v = acc[m][n][j] + b;
                    if (MODE == 0) {
                        // exact gelu (approximate=False): 0.5*x*(1+erf(x/sqrt(2)))
                        const float g = 0.5f * v * (1.f + erff(v * 0.70710678118654752f));
                        Y1[(size_t)pos * FDIM + col] = __float2bfloat16(g);
                    } else {
                        const unsigned code = list_tok[pos];
                        const float w = list_w[pos];
                        r[(size_t)code * HDIM + col] = v * w;
                    }
                }
            }
        }
    }
}

// ---------------- combine: out = hidden + r[2t] + r[2t+1] ----------------
__global__ void combine_kernel(const float* __restrict__ hidden, const float* __restrict__ r,
                               float* __restrict__ out) {
    const size_t n4 = (size_t)T_TOK * HDIM / 4;
    const size_t stride = (size_t)gridDim.x * blockDim.x;
    for (size_t i = (size_t)blockIdx.x * blockDim.x + threadIdx.x; i < n4; i += stride) {
        const size_t t = i / (HDIM / 4);
        const size_t h4 = i % (HDIM / 4);
        const float4 a = ((const float4*)hidden)[i];
        const float4 x = ((const float4*)r)[(t * 2) * (HDIM / 4) + h4];
        const float4 y = ((const float4*)r)[(t * 2 + 1) * (HDIM / 4) + h4];
        float4 o;
        o.x = a.x + x.x + y.x; o.y = a.y + x.y + y.y;
        o.z = a.z + x.z + y.z; o.w = a.w + x.w + y.w;
        ((float4*)out)[i] = o;
    }
}

static inline size_t alignup(size_t x) { return (x + 255) & ~(size_t)255; }

extern "C" void kernel_launch(void* const* d_in, const int* in_sizes, int n_in,
                              void* d_out, int out_size, void* d_ws, size_t ws_size,
                              hipStream_t stream) {
    const float* hidden = (const float*)d_in[0];
    const float* gate_w = (const float*)d_in[1];
    const float* w1     = (const float*)d_in[2];
    const float* b1     = (const float*)d_in[3];
    const float* w2     = (const float*)d_in[4];
    const float* b2     = (const float*)d_in[5];
    float* out = (float*)d_out;

    // workspace carve (~336 MB)
    char* p = (char*)d_ws;
    __hip_bfloat16* X  = (__hip_bfloat16*)p; p += alignup((size_t)T_TOK * HDIM * 2);
    __hip_bfloat16* Wt = (__hip_bfloat16*)p; p += alignup((size_t)FDIM * HDIM * 2);
    __hip_bfloat16* Y1 = (__hip_bfloat16*)p; p += alignup((size_t)T_TOK * FDIM * 2);
    float*    rbuf     = (float*)p;          p += alignup((size_t)2 * T_TOK * HDIM * 4);
    unsigned* list_tok = (unsigned*)p;       p += alignup((size_t)NEXP * T_TOK * 4);
    float*    list_w   = (float*)p;          p += alignup((size_t)NEXP * T_TOK * 4);
    int*      counts   = (int*)p;            p += alignup(NEXP * 4);

    zero_counts_kernel<<<1, 64, 0, stream>>>(counts);
    gate_kernel<<<T_TOK / 4, 256, 0, stream>>>(hidden, gate_w, X, list_tok, list_w, counts);

    for (int e = 0; e < NEXP; ++e) {
        // W1[e]: [H][F] -> Wt [F][H]
        transpose_bf16_kernel<<<dim3(FDIM / 64, HDIM / 64), 256, 0, stream>>>(
            w1 + (size_t)e * HDIM * FDIM, Wt, HDIM, FDIM);
        moe_gemm_kernel<0><<<dim3(FDIM / 128, T_TOK / 128), 256, 0, stream>>>(
            X, Wt, b1 + (size_t)e * FDIM, list_tok + e * T_TOK, list_w + e * T_TOK,
            counts + e, HDIM, FDIM, Y1, nullptr);
        // W2[e]: [F][H] -> Wt [H][F]
        transpose_bf16_kernel<<<dim3(HDIM / 64, FDIM / 64), 256, 0, stream>>>(
            w2 + (size_t)e * FDIM * HDIM, Wt, FDIM, HDIM);
        moe_gemm_kernel<1><<<dim3(HDIM / 128, T_TOK / 128), 256, 0, stream>>>(
            Y1, Wt, b2 + (size_t)e * HDIM, list_tok + e * T_TOK, list_w + e * T_TOK,
            counts + e, FDIM, HDIM, nullptr, rbuf);
    }

    combine_kernel<<<2048, 256, 0, stream>>>(hidden, rbuf, out);
}